// Round 16
// baseline (369.023 us; speedup 1.0000x reference)
//
#include <hip/hip_runtime.h>

#ifndef __has_builtin
#define __has_builtin(x) 0
#endif

#define T_STEPS 512
#define BATCH   128
#define DIN     256
#define HID     256
#define WPLD    (DIN + HID)   // 512

// Volatile asm loads: results are NOT rematerializable (cheap insurance).
#define ASM_LOAD4(dst, ptr) \
    asm volatile("global_load_dwordx4 %0, %1, off" : "=v"(dst) : "v"(ptr))
#define ASM_LOAD1(dst, ptr) \
    asm volatile("global_load_dword %0, %1, off" : "=v"(dst) : "v"(ptr))

// Barrier WITHOUT vmcnt drain (verified R11): waits only LDS ops; global
// h-stores stay in flight across it.
#define STEP_BARRIER() do {                                   \
    asm volatile("s_waitcnt lgkmcnt(0)" ::: "memory");        \
    __builtin_amdgcn_s_barrier();                             \
    __builtin_amdgcn_sched_barrier(0);                        \
} while (0)

// ---------------- cross-lane helpers (all verified in passing runs) ----------------
template<int CTRL>
__device__ __forceinline__ float dppmov(float x) {
    // 0xB1=quad xor1, 0x4E=quad xor2
    return __int_as_float(__builtin_amdgcn_update_dpp(0, __float_as_int(x), CTRL, 0xF, 0xF, true));
}
template<int PAT>
__device__ __forceinline__ float swz(float x) {
    // ds_swizzle BitMode: 0x101F=xor4, 0x201F=xor8, 0x401F=xor16
    return __int_as_float(__builtin_amdgcn_ds_swizzle(__float_as_int(x), PAT));
}
__device__ __forceinline__ float rcp_f(float x) {
#if __has_builtin(__builtin_amdgcn_rcpf)
    return __builtin_amdgcn_rcpf(x);
#else
    return 1.0f / x;
#endif
}

// ---------------------------------------------------------------------------
// Kernel 1: px[b][t][q] = sum_d x[t,b,d]*Wp[q,d] + qp[q]   (unchanged, verified)
// ---------------------------------------------------------------------------
__global__ __launch_bounds__(256) void qlstm_projx(const float* __restrict__ x,
                                                   const float* __restrict__ Wp,
                                                   const float* __restrict__ qp,
                                                   float* __restrict__ px) {
    const int wave = threadIdx.x >> 6;
    const int lane = threadIdx.x & 63;
    const int row  = blockIdx.x * 4 + wave;       // row = t*BATCH + b

    const float4 xv = ((const float4*)(x + (size_t)row * DIN))[lane];
    float acc[8];
#pragma unroll
    for (int Q = 0; Q < 8; ++Q) {
        float4 w = ((const float4*)(Wp + Q * WPLD))[lane];
        acc[Q] = xv.x * w.x + xv.y * w.y + xv.z * w.z + xv.w * w.w;
    }
#pragma unroll
    for (int Q = 0; Q < 8; ++Q) {
        acc[Q] += dppmov<0xB1>(acc[Q]);
        acc[Q] += dppmov<0x4E>(acc[Q]);
        acc[Q] += swz<0x101F>(acc[Q]);
    }
    float p = acc[0];
#pragma unroll
    for (int j = 1; j < 8; ++j) p = ((lane & 7) == j) ? acc[j] : p;
    p += swz<0x201F>(p);
    p += swz<0x401F>(p);
    p += __shfl_xor(p, 32);
    if (lane < 8) {
        const int bb = row & (BATCH - 1);
        const int tt = row >> 7;
        px[(size_t)bb * (T_STEPS * 8) + tt * 8 + lane] = p + qp[lane];
    }
}

// ---------------------------------------------------------------------------
// Kernel 2: recurrence, ONE barrier per step.
// h NEVER touches LDS: thread (w,l) owns column cg=64w+l; phase A computes
// per-lane partials p[q] = h_own * wph[q] over the wave's OWN 64 columns and
// wave-reduces them (projx-verified butterfly); lanes 0-7 publish raw
// partials part[t&1][q][w]. One barrier. Phase B: one ds_read_b128 gathers
// the 4 waves' partials for q=l>>3, sum + px + ONE cos per lane, then the
// R2-verified butterfly-collect broadcasts all 8 C's; prefix/gates/LSTM as
// R12 (verified); h stays in a register. part[] is double-buffered so the
// single barrier separates every read from the subsequent overwrite.
// ---------------------------------------------------------------------------
__global__ __launch_bounds__(256, 1) void qlstm_seq(const float* __restrict__ hx,
                                                    const float* __restrict__ cx,
                                                    const float* __restrict__ Wp,
                                                    const float* __restrict__ Wg,
                                                    const float* __restrict__ bg,
                                                    const float* __restrict__ px,
                                                    float* __restrict__ out) {
    __shared__ float px_lds[(T_STEPS + 1) * 8];   // +8 pad for prefetch overrun
    __shared__ float part[2][8][4];               // [buf][q][wave] raw partials

    const int tid = threadIdx.x;
    const int w   = tid >> 6;     // wave id 0..3
    const int l   = tid & 63;     // lane
    const int b   = blockIdx.x;
    const int cg  = tid;          // this thread's column (owns h[cg], c[cg])
    const int qb  = l >> 3;       // phase-B q assignment (R2 layout)

    // ---- weight loads (asm: non-rematerializable) ----
    float wph[8];                 // Wp[q][256+cg] — own column's proj weights
#pragma unroll
    for (int q = 0; q < 8; ++q) {
        const float* a = Wp + q * WPLD + DIN + cg;
        ASM_LOAD1(wph[q], a);
    }
    float4 WG0[4], WG1[4];        // Wg row (G*256+cg), floats 0..7
#pragma unroll
    for (int G = 0; G < 4; ++G) {
        const float* r = Wg + (size_t)(G * HID + cg) * 8;
        ASM_LOAD4(WG0[G], r);
        ASM_LOAD4(WG1[G], r + 4);
    }
    float bgc[4];                 // bg[G*256+cg]
#pragma unroll
    for (int G = 0; G < 4; ++G) {
        const float* a = bg + G * HID + cg;
        ASM_LOAD1(bgc[G], a);
    }

    // preload all px for this b (4096 floats = 1024 float4, 4 per thread)
    {
        const float4* pg = (const float4*)(px + (size_t)b * (T_STEPS * 8));
        float4* pl = (float4*)px_lds;
#pragma unroll
        for (int j = 0; j < 4; ++j) pl[j * 256 + tid] = pg[j * 256 + tid];
    }

    float hreg = hx[b * HID + cg];
    float c    = cx[b * HID + cg];

    asm volatile("s_waitcnt vmcnt(0)" ::: "memory");
    __builtin_amdgcn_sched_barrier(0);
    __syncthreads();   // px_lds ready (prologue only)

    float pxq = px_lds[qb];   // px[t=0][qb], prefetched

    float* outp = out + (size_t)b * HID + cg;

    for (int t = 0; t < T_STEPS; ++t) {
        // ---- phase A: partials over this wave's own 64 columns (h in reg) ----
        float acc[8];
#pragma unroll
        for (int q = 0; q < 8; ++q) acc[q] = hreg * wph[q];
        // projx-verified in-group butterfly (sum within aligned 8-lane group)
#pragma unroll
        for (int q = 0; q < 8; ++q) {
            acc[q] += dppmov<0xB1>(acc[q]);
            acc[q] += dppmov<0x4E>(acc[q]);
            acc[q] += swz<0x101F>(acc[q]);
        }
        // lane carries q = l&7, then cross-group sum (xor8/16/32)
        float p = acc[0];
#pragma unroll
        for (int j = 1; j < 8; ++j) p = ((l & 7) == j) ? acc[j] : p;
        p += swz<0x201F>(p);
        p += swz<0x401F>(p);
        p += __shfl_xor(p, 32);
        // lanes 0-7 publish this wave's raw partial for q=l
        if (l < 8) part[t & 1][l][w] = p;

        STEP_BARRIER();   // the ONLY barrier per step

        // ---- phase B: gather partials, cos, collect, gates, LSTM ----
        const float4 f4 = *(const float4*)&part[t & 1][qb][0];
        const float S  = ((f4.x + f4.y) + (f4.z + f4.w)) + pxq;
        const float cw = __cosf(S);          // ONE cos per lane (its q=qb)

        pxq = px_lds[(t + 1) * 8 + qb];      // prefetch next px (off-path)

        // R2-verified butterfly-collect: all 8 C's into every lane
        float o8 = swz<0x201F>(cw);
        float x0 = (l & 8) ? o8 : cw;
        float x1 = (l & 8) ? cw : o8;
        float y0 = swz<0x401F>(x0), y1 = swz<0x401F>(x1);
        float b0 = (l & 16) ? y0 : x0;
        float b1 = (l & 16) ? y1 : x1;
        float b2 = (l & 16) ? x0 : y0;
        float b3 = (l & 16) ? x1 : y1;
        float z0 = __shfl_xor(b0, 32), z1 = __shfl_xor(b1, 32);
        float z2 = __shfl_xor(b2, 32), z3 = __shfl_xor(b3, 32);
        const float C0 = (l & 32) ? z0 : b0;
        const float C1 = (l & 32) ? z1 : b1;
        const float C2 = (l & 32) ? z2 : b2;
        const float C3 = (l & 32) ? z3 : b3;
        const float C4 = (l & 32) ? b0 : z0;
        const float C5 = (l & 32) ? b1 : z1;
        const float C6 = (l & 32) ? b2 : z2;
        const float C7 = (l & 32) ? b3 : z3;

        // prefix products: qo[0]=C1..C7, qo[k>=1]=C0..Ck
        const float d01 = C0 * C1, d23 = C2 * C3, d45 = C4 * C5, d67 = C6 * C7;
        float qo[8];
        qo[1] = d01;
        qo[2] = d01 * C2;
        qo[3] = d01 * d23;
        qo[4] = qo[3] * C4;
        qo[5] = qo[3] * d45;
        qo[6] = qo[5] * C6;
        qo[7] = qo[5] * d67;
        qo[0] = (C1 * d23) * (d45 * d67);

        // gates for this thread's single column (tree-structured, as R12)
        float gf, gi, gg, go;
        {
            float a0, a1;
            a0 = fmaf(WG0[0].x, qo[0], bgc[0]);  a0 = fmaf(WG0[0].y, qo[1], a0);
            a0 = fmaf(WG0[0].z, qo[2], a0);      a0 = fmaf(WG0[0].w, qo[3], a0);
            a1 = WG1[0].x * qo[4];               a1 = fmaf(WG1[0].y, qo[5], a1);
            a1 = fmaf(WG1[0].z, qo[6], a1);      a1 = fmaf(WG1[0].w, qo[7], a1);
            gf = a0 + a1;
            a0 = fmaf(WG0[1].x, qo[0], bgc[1]);  a0 = fmaf(WG0[1].y, qo[1], a0);
            a0 = fmaf(WG0[1].z, qo[2], a0);      a0 = fmaf(WG0[1].w, qo[3], a0);
            a1 = WG1[1].x * qo[4];               a1 = fmaf(WG1[1].y, qo[5], a1);
            a1 = fmaf(WG1[1].z, qo[6], a1);      a1 = fmaf(WG1[1].w, qo[7], a1);
            gi = a0 + a1;
            a0 = fmaf(WG0[2].x, qo[0], bgc[2]);  a0 = fmaf(WG0[2].y, qo[1], a0);
            a0 = fmaf(WG0[2].z, qo[2], a0);      a0 = fmaf(WG0[2].w, qo[3], a0);
            a1 = WG1[2].x * qo[4];               a1 = fmaf(WG1[2].y, qo[5], a1);
            a1 = fmaf(WG1[2].z, qo[6], a1);      a1 = fmaf(WG1[2].w, qo[7], a1);
            gg = a0 + a1;
            a0 = fmaf(WG0[3].x, qo[0], bgc[3]);  a0 = fmaf(WG0[3].y, qo[1], a0);
            a0 = fmaf(WG0[3].z, qo[2], a0);      a0 = fmaf(WG0[3].w, qo[3], a0);
            a1 = WG1[3].x * qo[4];               a1 = fmaf(WG1[3].y, qo[5], a1);
            a1 = fmaf(WG1[3].z, qo[6], a1);      a1 = fmaf(WG1[3].w, qo[7], a1);
            go = a0 + a1;
        }

        // LSTM pointwise, parallel form (inf-safe, no clamp) — as R12
        const float sf = rcp_f(1.f + __expf(-gf));
        const float si = rcp_f(1.f + __expf(-gi));
        const float so = rcp_f(1.f + __expf(-go));
        const float tg = 1.f - 2.f * rcp_f(__expf(2.f * gg) + 1.f);
        const float cn = fmaf(sf, c, si * tg);
        const float th = 1.f - 2.f * rcp_f(__expf(2.f * cn) + 1.f);
        const float h  = so * th;
        c = cn;

        *outp = h;                   // global store; not drained at barrier
        outp += BATCH * HID;

        hreg = h;                    // h stays in register — no LDS publish!
    }

    const size_t base = (size_t)T_STEPS * BATCH * HID;
    out[base + b * HID + cg] = hreg;
    out[base + BATCH * HID + b * HID + cg] = c;
}

extern "C" void kernel_launch(void* const* d_in, const int* in_sizes, int n_in,
                              void* d_out, int out_size, void* d_ws, size_t ws_size,
                              hipStream_t stream) {
    const float* x   = (const float*)d_in[0];   // (512,128,256)
    const float* hx  = (const float*)d_in[1];   // (128,256)
    const float* cx  = (const float*)d_in[2];   // (128,256)
    const float* Wp  = (const float*)d_in[3];   // (8,512)
    const float* qp  = (const float*)d_in[4];   // (8,)
    const float* Wg  = (const float*)d_in[5];   // (1024,8)
    const float* bg  = (const float*)d_in[6];   // (1024,)
    float* out = (float*)d_out;
    float* px  = (float*)d_ws;                  // 128*512*8 floats = 2 MB

    qlstm_projx<<<(T_STEPS * BATCH) / 4, 256, 0, stream>>>(x, Wp, qp, px);
    qlstm_seq<<<BATCH, 256, 0, stream>>>(hx, cx, Wp, Wg, bg, px, out);
}